// Round 12
// baseline (213.461 us; speedup 1.0000x reference)
//
#include <hip/hip_runtime.h>
#include <stdint.h>
#include <stddef.h>

// Problem geometry (B=4, S=2048, DIN=4096, DOUT=4096)
constexpr int MDIM = 8192;   // B*S
constexpr int NDIM = 4096;   // DOUT
constexpr int KDIM = 4096;   // DIN

using f32x4  = __attribute__((ext_vector_type(4)))  float;
using s16x4  = __attribute__((ext_vector_type(4)))  short;
using s16x8  = __attribute__((ext_vector_type(8)))  short;
using i32x4  = __attribute__((ext_vector_type(4)))  int;
using i32x16 = __attribute__((ext_vector_type(16))) int;

__device__ __forceinline__ short f32_to_bf16_rn(float f) {
  union { float f; uint32_t u; } v; v.f = f;
  uint32_t r = (v.u + 0x7FFFu + ((v.u >> 16) & 1u)) >> 16;  // RTN-even
  return (short)(uint16_t)r;
}

// ---------------- prepass 1: x f32 -> i8, per-row symmetric scale ----------------
__global__ void __launch_bounds__(256) quant_x_kernel(const float* __restrict__ in,
                                                      signed char* __restrict__ out,
                                                      float* __restrict__ sx) {
  const int row = blockIdx.x;
  const int t   = threadIdx.x;
  const float* rp = in + (size_t)row * KDIM;
  f32x4 v[4];
  float m = 0.0f;
#pragma unroll
  for (int j = 0; j < 4; ++j) {
    v[j] = *(const f32x4*)(rp + t * 16 + j * 4);
#pragma unroll
    for (int e = 0; e < 4; ++e) m = fmaxf(m, __builtin_fabsf(v[j][e]));
  }
#pragma unroll
  for (int off = 32; off > 0; off >>= 1) m = fmaxf(m, __shfl_xor(m, off, 64));
  __shared__ float wmax[4];
  const int wv = t >> 6, ln = t & 63;
  if (ln == 0) wmax[wv] = m;
  __syncthreads();
  m = fmaxf(fmaxf(wmax[0], wmax[1]), fmaxf(wmax[2], wmax[3]));
  const float inv = (m > 0.0f) ? (127.0f / m) : 0.0f;
  if (t == 0) sx[row] = m * (1.0f / 127.0f);
  i32x4 o;
#pragma unroll
  for (int j = 0; j < 4; ++j) {
    int b[4];
#pragma unroll
    for (int e = 0; e < 4; ++e) {
      int q = (int)rintf(v[j][e] * inv);
      q = q < -127 ? -127 : (q > 127 ? 127 : q);
      b[e] = q & 255;
    }
    o[j] = b[0] | (b[1] << 8) | (b[2] << 16) | (b[3] << 24);
  }
  *(i32x4*)(out + (size_t)row * KDIM + t * 16) = o;
}

// ---------------- prepass 2: weight int32 -> i8 (exact, low-byte pack) ----------------
__global__ void __launch_bounds__(256) quant_w_kernel(const int* __restrict__ in,
                                                      signed char* __restrict__ out, int n16) {
  int i = blockIdx.x * 256 + threadIdx.x;
  const int stride = gridDim.x * 256;
  for (; i < n16; i += stride) {
    const i32x4* p = (const i32x4*)(in + (size_t)i * 16);
    i32x4 o;
#pragma unroll
    for (int j = 0; j < 4; ++j) {
      i32x4 a = p[j];
      o[j] = (a[0] & 255) | ((a[1] & 255) << 8) | ((a[2] & 255) << 16) | ((a[3] & 255) << 24);
    }
    *(i32x4*)(out + (size_t)i * 16) = o;
  }
}

// =====================================================================
// 256x256 i8 GEMM, r11 ring schedule UNCHANGED, MFMA shape 32x32x32.
//   out = (i32 acc) * sx[row] * s_w + bias[col]
//
// LDS = 4 rotating buffers x 32 KB (A 16 KB @ +0, B 16 KB @ +16384).
// Region layout [256 rows][64 B] with SEGMENT swizzle: the four 16-B
// segments of row R are permuted phys_seg = seg ^ (R&3).
//   Read balance (enumerated): lane l (half h=l>>5, r=l&31, seg_lin=2ks+h):
//   bank-group g = (4(r&1) + (seg_lin ^ (r&3))) mod 8 -> each of 8 groups
//   hit exactly 8x per b128 across 64 lanes, both ks. Zero extra conflict.
// Stage decode (write side): thread t stages 16 B; row = chunk*128+(t>>2),
//   src col byte = tile*64 + ((t&3) ^ ((t>>2)&3))*16. Coalesced 64B/4thr.
//
// Frag maps (r4-validated 32x32 base + r8-validated i8 K-doubling):
//   A/B: row|col = lane&31, kbyte = ks*32 + (lane>>5)*16 + 0..15
//   C/D: col = lane&31, row = (reg&3) + 8*(reg>>2) + 4*(lane>>5)
//
// Window t (buf u=t&3, frag sets E/O by t&1):
//   { ds_read 12 frags(t+1) from buf[(t+1)&3] ; 4 GLL stage t+3 ;
//     16 MFMA 32x32x32 on frags(t) ; vmcnt(4) ; BAR }
// Ledger identical to r11 (4 GLL/thread/window, vmcnt(4) retires stage(t+2)).
// =====================================================================

#define BAR asm volatile("s_barrier" ::: "memory")
#define WAITVM(n) asm volatile("s_waitcnt vmcnt(" #n ")" ::: "memory")

#define GLL(src, dst) __builtin_amdgcn_global_load_lds(                     \
    (const __attribute__((address_space(1))) void*)(src),                   \
    (__attribute__((address_space(3))) void*)(dst), 16, 0, 0)

// prologue: stage tile tau into buf tau (tau = 0,1,2)
#define STGP(tau) do {                                                      \
  GLL(Arow + (size_t)r0 * 4096 + (tau) * 64 + cb,                           \
      lds + (tau) * 32768 + t * 16);                                        \
  GLL(Arow + (size_t)(128 + r0) * 4096 + (tau) * 64 + cb,                   \
      lds + (tau) * 32768 + 8192 + t * 16);                                 \
  GLL(Brow + (size_t)r0 * 4096 + (tau) * 64 + cb,                           \
      lds + (tau) * 32768 + 16384 + t * 16);                                \
  GLL(Brow + (size_t)(128 + r0) * 4096 + (tau) * 64 + cb,                   \
      lds + (tau) * 32768 + 16384 + 8192 + t * 16);                         \
} while (0)

// in-loop: advancing per-thread source pointers (start at tile 3 cols)
#define STGL(u3) do {                                                       \
  GLL(aSrc0, lds + (u3) * 32768 + t * 16);                                  \
  GLL(aSrc1, lds + (u3) * 32768 + 8192 + t * 16);                           \
  GLL(bSrc0, lds + (u3) * 32768 + 16384 + t * 16);                          \
  GLL(bSrc1, lds + (u3) * 32768 + 16384 + 8192 + t * 16);                   \
  aSrc0 += 64; aSrc1 += 64; bSrc0 += 64; bSrc1 += 64;                       \
} while (0)

// frag reads: fi rows stride 32 -> 2048 B; ks selects loffK0/loffK1
#define LDA32(u, fi, ks) (*(const i32x4*)(lds + (u) * 32768                 \
    + wm * 8192 + (fi) * 2048 + ((ks) ? loffK1 : loffK0)))
#define LDB32(u, fj, ks) (*(const i32x4*)(lds + (u) * 32768 + 16384         \
    + wn * 4096 + (fj) * 2048 + ((ks) ? loffK1 : loffK0)))

// One window. AFC/BFC current frag set (af[fi*2+ks], bf[fj*2+ks]).
#define WIN(u, AFC, BFC, AFN, BFN, dord, dostg, vmarg) do {                 \
  if (dord) {                                                               \
    _Pragma("unroll") for (int i_ = 0; i_ < 4; ++i_) {                      \
      AFN[i_ * 2]     = LDA32(((u) + 1) & 3, i_, 0);                        \
      AFN[i_ * 2 + 1] = LDA32(((u) + 1) & 3, i_, 1);                        \
    }                                                                       \
    _Pragma("unroll") for (int j_ = 0; j_ < 2; ++j_) {                      \
      BFN[j_ * 2]     = LDB32(((u) + 1) & 3, j_, 0);                        \
      BFN[j_ * 2 + 1] = LDB32(((u) + 1) & 3, j_, 1);                        \
    }                                                                       \
  }                                                                         \
  if (dostg) STGL(((u) + 3) & 3);                                           \
  __builtin_amdgcn_s_setprio(1);                                            \
  _Pragma("unroll") for (int ks_ = 0; ks_ < 2; ++ks_)                       \
  _Pragma("unroll") for (int i_ = 0; i_ < 4; ++i_)                          \
  _Pragma("unroll") for (int j_ = 0; j_ < 2; ++j_)                          \
    acc[i_][j_] = __builtin_amdgcn_mfma_i32_32x32x32_i8(                    \
        AFC[i_ * 2 + ks_], BFC[j_ * 2 + ks_], acc[i_][j_], 0, 0, 0);        \
  __builtin_amdgcn_s_setprio(0);                                            \
  if ((vmarg) == 4) { WAITVM(4); } else if ((vmarg) == 0) { WAITVM(0); }    \
  BAR;                                                                      \
} while (0)

__global__ void __launch_bounds__(512, 1) gemm_i8_ring32(
    const signed char* __restrict__ A, const signed char* __restrict__ Bw,
    const float* __restrict__ sx, const float* __restrict__ scale_p,
    const float* __restrict__ bias, float* __restrict__ out) {
  __shared__ __align__(16) char lds[131072];   // 4 bufs x (A 16K + B 16K)

  const int t      = threadIdx.x;        // 0..511
  const int lane   = t & 63;
  const int wave   = t >> 6;
  const int wm     = wave >> 2;          // 0..1  (row half: 128 rows)
  const int wn     = wave & 3;           // 0..3  (col quarter: 64 cols)
  const int l31    = lane & 31;
  const int lh     = lane >> 5;          // 0..1

  // seg-swizzled read offsets: row part + permuted 16B segment (ks 0/1)
  const int loffK0 = l31 * 64 + ((lh)     ^ (l31 & 3)) * 16;
  const int loffK1 = l31 * 64 + ((2 + lh) ^ (l31 & 3)) * 16;

  // stage decode: thread t writes LDS slot t*16 (+chunk*8192); the slot's
  // phys_seg = t&3 must receive logical seg = (t&3) ^ (row&3), row = t>>2.
  const int r0 = t >> 2;                              // row 0..127 in chunk
  const int cb = (((t & 3) ^ ((t >> 2) & 3)) << 4);   // source col byte

  // XCD-aware swizzle: nwg = 512 (divisible by 8)
  const int bid   = blockIdx.x;
  const int wg    = (bid & 7) * 64 + (bid >> 3);
  const int ntile = wg & 15;             // 16 n-tiles
  const int mtile = wg >> 4;             // 32 m-tiles
  const int m0 = mtile * 256;
  const int n0 = ntile * 256;

  const char* Arow = (const char*)(A + (size_t)m0 * KDIM);
  const char* Brow = (const char*)(Bw + (size_t)n0 * KDIM);

  const char* aSrc0 = Arow + (size_t)r0 * 4096 + 192 + cb;
  const char* aSrc1 = Arow + (size_t)(128 + r0) * 4096 + 192 + cb;
  const char* bSrc0 = Brow + (size_t)r0 * 4096 + 192 + cb;
  const char* bSrc1 = Brow + (size_t)(128 + r0) * 4096 + 192 + cb;

  i32x16 acc[4][2] = {};
  i32x4 afE[8], afO[8], bfE[4], bfO[4];

  // Prologue: stage tiles 0,1,2 (12 GLL/thread).
  STGP(0);
  STGP(1);
  STGP(2);
  WAITVM(8);   // retire stage(0)
  BAR;
#pragma unroll
  for (int i_ = 0; i_ < 4; ++i_) {
    afE[i_ * 2]     = LDA32(0, i_, 0);
    afE[i_ * 2 + 1] = LDA32(0, i_, 1);
  }
#pragma unroll
  for (int j_ = 0; j_ < 2; ++j_) {
    bfE[j_ * 2]     = LDB32(0, j_, 0);
    bfE[j_ * 2 + 1] = LDB32(0, j_, 1);
  }
  WAITVM(4);   // retire stage(1) -> buf1 valid for window 0's reads
  BAR;

  // Main: windows 0..59 (stage tiles 3..62), then tail 60..63.
#pragma unroll 1
  for (int tp = 0; tp < 15; ++tp) {
    WIN(0, afE, bfE, afO, bfO, 1, 1, 4);
    WIN(1, afO, bfO, afE, bfE, 1, 1, 4);
    WIN(2, afE, bfE, afO, bfO, 1, 1, 4);
    WIN(3, afO, bfO, afE, bfE, 1, 1, 4);
  }
  WIN(0, afE, bfE, afO, bfO, 1, 1, 4);   // t=60: stages tile 63
  WIN(1, afO, bfO, afE, bfE, 1, 0, 0);   // t=61: drain stage(63)
  WIN(2, afE, bfE, afO, bfO, 1, 0, -1);  // t=62: reads frags(63)
  WIN(3, afO, bfO, afE, bfE, 0, 0, -1);  // t=63: MFMA only

  // Epilogue: 32x32 D layout col=lane&31, row=(reg&3)+8*(reg>>2)+4*(lane>>5)
  // (m74/m101-verified; dtype-independent). out = acc*sx[row]*sw + bias.
  const float sw = scale_p[0];
  float bv[2];
#pragma unroll
  for (int j = 0; j < 2; ++j) bv[j] = bias[n0 + wn * 64 + j * 32 + l31];
#pragma unroll
  for (int fi = 0; fi < 4; ++fi) {
    const int rowbase = m0 + wm * 128 + fi * 32 + lh * 4;
#pragma unroll
    for (int reg = 0; reg < 16; ++reg) {
      const int row = rowbase + (reg & 3) + ((reg >> 2) << 3);
      const float sxr = sx[row] * sw;
#pragma unroll
      for (int j = 0; j < 2; ++j) {
        const int col = n0 + wn * 64 + j * 32 + l31;
        out[(size_t)row * NDIM + col] = (float)acc[fi][j][reg] * sxr + bv[j];
      }
    }
  }
}

// ---------------- fallback: m97-style bf16 reg-staging (ws too small) ----------------
constexpr int FTILE = 128;
constexpr int FBK   = 64;

__global__ void __launch_bounds__(256) gemm_raw(
    const float* __restrict__ X, const int* __restrict__ W,
    const float* __restrict__ scale_p, const float* __restrict__ bias,
    float* __restrict__ out) {
  __shared__ short As[FTILE * FBK];
  __shared__ short Bs[FTILE * FBK];

  const int t      = threadIdx.x;
  const int lane   = t & 63;
  const int wave   = t >> 6;
  const int wm     = wave >> 1;
  const int wn     = wave & 1;
  const int lane15   = lane & 15;
  const int laneHalf = lane >> 4;

  const int bid   = blockIdx.x;
  const int wg    = (bid & 7) * 256 + (bid >> 3);
  const int ntile = wg & 31;
  const int mtile = wg >> 5;
  const int m0 = mtile * FTILE;
  const int n0 = ntile * FTILE;

  f32x4 acc[4][4] = {};

  for (int k0 = 0; k0 < KDIM; k0 += FBK) {
    __syncthreads();
#pragma unroll
    for (int r = 0; r < 8; ++r) {
      const int f   = r * 256 + t;
      const int row = f >> 4;
      const int c4  = (f & 15) * 4;
      f32x4 v = *(const f32x4*)(X + (size_t)(m0 + row) * KDIM + (k0 + c4));
      s16x4 h;
#pragma unroll
      for (int j = 0; j < 4; ++j) h[j] = f32_to_bf16_rn(v[j]);
      *(s16x4*)&As[row * FBK + c4] = h;

      i32x4 wv = *(const i32x4*)(W + (size_t)(n0 + row) * KDIM + (k0 + c4));
      s16x4 hw;
#pragma unroll
      for (int j = 0; j < 4; ++j) hw[j] = f32_to_bf16_rn((float)wv[j]);
      *(s16x4*)&Bs[row * FBK + c4] = hw;
    }
    __syncthreads();

#pragma unroll
    for (int kk = 0; kk < FBK; kk += 32) {
      const int kb = kk + laneHalf * 8;
      s16x8 af[4], bf[4];
#pragma unroll
      for (int i = 0; i < 4; ++i) {
        af[i] = *(const s16x8*)&As[(wm * 64 + i * 16 + lane15) * FBK + kb];
        bf[i] = *(const s16x8*)&Bs[(wn * 64 + i * 16 + lane15) * FBK + kb];
      }
#pragma unroll
      for (int i = 0; i < 4; ++i)
#pragma unroll
        for (int j = 0; j < 4; ++j)
          acc[i][j] = __builtin_amdgcn_mfma_f32_16x16x32_bf16(af[i], bf[j], acc[i][j], 0, 0, 0);
    }
  }

  const float s = scale_p[0];
#pragma unroll
  for (int j = 0; j < 4; ++j) {
    const int col = n0 + wn * 64 + j * 16 + lane15;
    const float bv = bias[col];
#pragma unroll
    for (int i = 0; i < 4; ++i) {
      const int row = m0 + wm * 64 + i * 16 + laneHalf * 4;
#pragma unroll
      for (int q = 0; q < 4; ++q)
        out[(size_t)(row + q) * NDIM + col] = acc[i][j][q] * s + bv;
    }
  }
}

extern "C" void kernel_launch(void* const* d_in, const int* in_sizes, int n_in,
                              void* d_out, int out_size, void* d_ws, size_t ws_size,
                              hipStream_t stream) {
  const float* x     = (const float*)d_in[0];
  const int*   w     = (const int*)d_in[1];    // integer inputs materialize as int32
  const float* scale = (const float*)d_in[2];
  const float* bias  = (const float*)d_in[3];
  float* out = (float*)d_out;

  const size_t a_bytes = (size_t)MDIM * KDIM;            // 33,554,432 (i8)
  const size_t b_bytes = (size_t)NDIM * KDIM;            // 16,777,216 (i8)
  const size_t need    = a_bytes + b_bytes + MDIM * 4;   // + sx floats

  if (ws_size >= need) {
    signed char* Ai8 = (signed char*)d_ws;
    signed char* Bi8 = Ai8 + a_bytes;
    float*       sxp = (float*)(Bi8 + b_bytes);
    quant_x_kernel<<<MDIM, 256, 0, stream>>>(x, Ai8, sxp);
    quant_w_kernel<<<4096, 256, 0, stream>>>(w, Bi8, (int)(b_bytes / 16));
    const int nwg = (MDIM / 256) * (NDIM / 256);  // 32*16 = 512
    gemm_i8_ring32<<<nwg, 512, 0, stream>>>(Ai8, Bi8, sxp, scale, bias, out);
  } else {
    const int nwg = (MDIM / FTILE) * (NDIM / FTILE);  // 2048
    gemm_raw<<<nwg, 256, 0, stream>>>(x, w, scale, bias, out);
  }
}

// Round 13
// 185.589 us; speedup vs baseline: 1.1502x; 1.1502x over previous
//
#include <hip/hip_runtime.h>
#include <stdint.h>
#include <stddef.h>

// Problem geometry (B=4, S=2048, DIN=4096, DOUT=4096)
constexpr int MDIM = 8192;   // B*S
constexpr int NDIM = 4096;   // DOUT
constexpr int KDIM = 4096;   // DIN

using f32x4 = __attribute__((ext_vector_type(4))) float;
using s16x4 = __attribute__((ext_vector_type(4))) short;
using i32x4 = __attribute__((ext_vector_type(4))) int;

__device__ __forceinline__ short f32_to_bf16_rn(float f) {
  union { float f; uint32_t u; } v; v.f = f;
  uint32_t r = (v.u + 0x7FFFu + ((v.u >> 16) & 1u)) >> 16;  // RTN-even
  return (short)(uint16_t)r;
}

// ---------------- prepass 1: x f32 -> i8, per-row symmetric scale ----------------
__global__ void __launch_bounds__(256) quant_x_kernel(const float* __restrict__ in,
                                                      signed char* __restrict__ out,
                                                      float* __restrict__ sx) {
  const int row = blockIdx.x;
  const int t   = threadIdx.x;
  const float* rp = in + (size_t)row * KDIM;
  f32x4 v[4];
  float m = 0.0f;
#pragma unroll
  for (int j = 0; j < 4; ++j) {
    v[j] = *(const f32x4*)(rp + t * 16 + j * 4);
#pragma unroll
    for (int e = 0; e < 4; ++e) m = fmaxf(m, __builtin_fabsf(v[j][e]));
  }
#pragma unroll
  for (int off = 32; off > 0; off >>= 1) m = fmaxf(m, __shfl_xor(m, off, 64));
  __shared__ float wmax[4];
  const int wv = t >> 6, ln = t & 63;
  if (ln == 0) wmax[wv] = m;
  __syncthreads();
  m = fmaxf(fmaxf(wmax[0], wmax[1]), fmaxf(wmax[2], wmax[3]));
  const float inv = (m > 0.0f) ? (127.0f / m) : 0.0f;
  if (t == 0) sx[row] = m * (1.0f / 127.0f);
  i32x4 o;
#pragma unroll
  for (int j = 0; j < 4; ++j) {
    int b[4];
#pragma unroll
    for (int e = 0; e < 4; ++e) {
      int q = (int)rintf(v[j][e] * inv);
      q = q < -127 ? -127 : (q > 127 ? 127 : q);
      b[e] = q & 255;
    }
    o[j] = b[0] | (b[1] << 8) | (b[2] << 16) | (b[3] << 24);
  }
  *(i32x4*)(out + (size_t)row * KDIM + t * 16) = o;
}

// ---------------- prepass 2: weight int32 -> i8 (exact, low-byte pack) ----------------
__global__ void __launch_bounds__(256) quant_w_kernel(const int* __restrict__ in,
                                                      signed char* __restrict__ out, int n16) {
  int i = blockIdx.x * 256 + threadIdx.x;
  const int stride = gridDim.x * 256;
  for (; i < n16; i += stride) {
    const i32x4* p = (const i32x4*)(in + (size_t)i * 16);
    i32x4 o;
#pragma unroll
    for (int j = 0; j < 4; ++j) {
      i32x4 a = p[j];
      o[j] = (a[0] & 255) | ((a[1] & 255) << 8) | ((a[2] & 255) << 16) | ((a[3] & 255) << 24);
    }
    *(i32x4*)(out + (size_t)i * 16) = o;
  }
}

// =====================================================================
// 256x256 i8 GEMM = BYTE-EXACT port of the verified round-3 bf16 8-phase
// kernel (same LDS map, laneoff, stage decode, schedule, vmcnt ledger);
// BK=128 i8 (128 B K-columns == round-3's 64 bf16), 32 K-tiles,
// MFMA 16x16x64 i8 (same 16-B frags as 16x16x32 bf16).
//   out = (i32 acc) * sx[row] * s_w + bias[col]
// LDS per matrix per buffer (32 KiB): [ks:2][256 rows][64 B],
// XOR swizzle phys = lin ^ (((lin>>9)&1)<<5)  (st_16x32).
// Half-tile stream order per K-tile: [B-ks0, A-ks0, B-ks1, A-ks1].
// =====================================================================

#define BAR asm volatile("s_barrier" ::: "memory")
#define WAITVM6 asm volatile("s_waitcnt vmcnt(6)" ::: "memory")
#define WAITVM0 asm volatile("s_waitcnt vmcnt(0)" ::: "memory")

#define GLL(src, dst) __builtin_amdgcn_global_load_lds(                     \
    (const __attribute__((address_space(1))) void*)(src),                   \
    (__attribute__((address_space(3))) void*)(dst), 16, 0, 0)

// grow: const char* global row base (matrix + tile_row0*KDIM), row stride 4096 B
// ldsmat: 0 (A) or 65536 (B)
#define STAGE(grow, ldsmat, ks, tau) do {                                   \
  const int buf_ = (tau) & 1;                                               \
  GLL((grow) + (size_t)r0 * 4096 + (size_t)(tau) * 128 + (ks) * 64 + cb,    \
      lds + (ldsmat) + buf_ * 32768 + (ks) * 16384 + t * 16);               \
  GLL((grow) + (size_t)r1 * 4096 + (size_t)(tau) * 128 + (ks) * 64 + cb,    \
      lds + (ldsmat) + buf_ * 32768 + (ks) * 16384 + 8192 + t * 16);        \
} while (0)

#define LDA(cur, ks, i) (*(const i32x4*)(lds + (cur) * 32768 + (ks) * 16384 \
    + (wm * 8 + (i)) * 1024 + laneoff))
#define LDB(cur, ks, j) (*(const i32x4*)(lds + 65536 + (cur) * 32768        \
    + (ks) * 16384 + (wn * 4 + (j)) * 1024 + laneoff))

#define READ_B(cur, ks) do {                                                \
  _Pragma("unroll") for (int j = 0; j < 4; ++j) bf[j] = LDB(cur, ks, j);    \
} while (0)
#define READ_A(cur, ks, ibase) do {                                         \
  _Pragma("unroll") for (int i = 0; i < 4; ++i) af[i] = LDA(cur, ks, (ibase) + i); \
} while (0)

#define MFMA16(ibase) do {                                                  \
  __builtin_amdgcn_s_setprio(1);                                            \
  _Pragma("unroll") for (int i = 0; i < 4; ++i)                             \
  _Pragma("unroll") for (int j = 0; j < 4; ++j)                             \
    acc[(ibase) + i][j] = __builtin_amdgcn_mfma_i32_16x16x64_i8(            \
        af[i], bf[j], acc[(ibase) + i][j], 0, 0, 0);                        \
  __builtin_amdgcn_s_setprio(0);                                            \
} while (0)

// One K-tile = 4 phases. nstage: 4=full stream, 1=only ph1 stage, 0=none.
// endvm: 6 -> vmcnt(6), 0 -> vmcnt(0), -1 -> none.
#define KTILE(t_, cur, nstage, endvm) do {                                  \
  /* ph1: ks0, frags 0-3 */                                                 \
  READ_B(cur, 0); READ_A(cur, 0, 0);                                        \
  if ((nstage) >= 1) STAGE(Arow, 0, 1, (t_) + 1);        /* t+1 q3: A-ks1 */\
  BAR; MFMA16(0); BAR;                                                      \
  /* ph2: ks0, frags 4-7 (reuse bf) */                                      \
  READ_A(cur, 0, 4);                                                        \
  if ((nstage) == 4) STAGE(Brow, 65536, 0, (t_) + 2);    /* t+2 q0: B-ks0 */\
  BAR; MFMA16(4); BAR;                                                      \
  /* ph3: ks1, frags 0-3 */                                                 \
  READ_B(cur, 1); READ_A(cur, 1, 0);                                        \
  if ((nstage) == 4) STAGE(Arow, 0, 0, (t_) + 2);        /* t+2 q1: A-ks0 */\
  BAR; MFMA16(0); BAR;                                                      \
  /* ph4: ks1, frags 4-7 */                                                 \
  READ_A(cur, 1, 4);                                                        \
  if ((nstage) == 4) STAGE(Brow, 65536, 1, (t_) + 2);    /* t+2 q2: B-ks1 */\
  BAR; MFMA16(4);                                                           \
  if ((endvm) == 6) { WAITVM6; } else if ((endvm) == 0) { WAITVM0; }        \
  BAR;                                                                      \
} while (0)

__global__ void __launch_bounds__(512, 2) gemm_i8_8ph(
    const signed char* __restrict__ A, const signed char* __restrict__ Bw,
    const float* __restrict__ sx, const float* __restrict__ scale_p,
    const float* __restrict__ bias, float* __restrict__ out) {
  __shared__ __align__(16) char lds[131072];

  const int t      = threadIdx.x;        // 0..511
  const int lane   = t & 63;
  const int wave   = t >> 6;
  const int wm     = wave >> 2;          // 0..1  (row half: 128 rows)
  const int wn     = wave & 3;           // 0..3  (col quarter: 64 cols)
  const int lane15 = lane & 15;
  const int lh     = lane >> 4;          // 0..3

  // round-3-verified zero-conflict swizzled read offset (XOR, not '+').
  const int laneoff = (lane15 * 64 + lh * 16) ^ ((lane15 & 8) << 2);

  // stage decode: LDS slot o = l*8192 + t*16 (+ks*16384) holds element at
  // a = o ^ (((o>>9)&1)<<5); here bit9 of o depends only on t.
  const int ax = ((t >> 5) & 1) << 5;
  const int a0 = (t * 16) ^ ax;
  const int a1 = (8192 + t * 16) ^ ax;
  const int r0 = (((a0 >> 10) & 15) << 4) | ((a0 >> 6) & 15);
  const int r1 = (((a1 >> 10) & 15) << 4) | ((a1 >> 6) & 15);
  const int cb = a0 & 63;                // col byte within 64B row (same for l=0,1)

  // XCD-aware swizzle: nwg = 512 (divisible by 8)
  const int bid   = blockIdx.x;
  const int wg    = (bid & 7) * 64 + (bid >> 3);
  const int ntile = wg & 15;             // 16 n-tiles
  const int mtile = wg >> 4;             // 32 m-tiles
  const int m0 = mtile * 256;
  const int n0 = ntile * 256;

  const char* Arow = (const char*)(A + (size_t)m0 * KDIM);
  const char* Brow = (const char*)(Bw + (size_t)n0 * KDIM);

  i32x4 acc[8][4] = {};
  i32x4 af[4], bf[4];

  // Prologue: tile0 (q0..q3) -> buf0, tile1 (q0..q2) -> buf1; 14 loads/thread.
  STAGE(Brow, 65536, 0, 0);
  STAGE(Arow, 0,     0, 0);
  STAGE(Brow, 65536, 1, 0);
  STAGE(Arow, 0,     1, 0);
  STAGE(Brow, 65536, 0, 1);
  STAGE(Arow, 0,     0, 1);
  STAGE(Brow, 65536, 1, 1);
  WAITVM6;   // tile0 fully landed; 3 half-tiles of tile1 in flight
  BAR;

  // Main: 32 K-tiles total (BK=128 i8); pairs keep buf index compile-time.
#pragma unroll 1
  for (int tp = 0; tp < 15; ++tp) {
    const int t2 = tp * 2;
    KTILE(t2,     0, 4, 6);
    KTILE(t2 + 1, 1, 4, 6);
  }
  KTILE(30, 0, 1, 0);    // issues last half (tile31 q3), then drain
  KTILE(31, 1, 0, -1);

  // Epilogue: D layout col=lane&15, row=(lane>>4)*4+q (shape-determined,
  // dtype-independent — m89/m121-128). out = acc * sx[row]*sw + bias.
  const float sw = scale_p[0];
  float bv[4];
#pragma unroll
  for (int j = 0; j < 4; ++j) bv[j] = bias[n0 + wn * 64 + j * 16 + lane15];
#pragma unroll
  for (int i = 0; i < 8; ++i) {
    const int rowb = m0 + wm * 128 + i * 16 + lh * 4;
    float sxq[4];
#pragma unroll
    for (int q = 0; q < 4; ++q) sxq[q] = sx[rowb + q] * sw;
#pragma unroll
    for (int j = 0; j < 4; ++j) {
      const int col = n0 + wn * 64 + j * 16 + lane15;
#pragma unroll
      for (int q = 0; q < 4; ++q)
        out[(size_t)(rowb + q) * NDIM + col] = (float)acc[i][j][q] * sxq[q] + bv[j];
    }
  }
}

// ---------------- fallback: m97-style bf16 reg-staging (ws too small) ----------------
constexpr int FTILE = 128;
constexpr int FBK   = 64;

__global__ void __launch_bounds__(256) gemm_raw(
    const float* __restrict__ X, const int* __restrict__ W,
    const float* __restrict__ scale_p, const float* __restrict__ bias,
    float* __restrict__ out) {
  __shared__ short As[FTILE * FBK];
  __shared__ short Bs[FTILE * FBK];

  const int t      = threadIdx.x;
  const int lane   = t & 63;
  const int wave   = t >> 6;
  const int wm     = wave >> 1;
  const int wn     = wave & 1;
  const int lane15   = lane & 15;
  const int laneHalf = lane >> 4;

  const int bid   = blockIdx.x;
  const int wg    = (bid & 7) * 256 + (bid >> 3);
  const int ntile = wg & 31;
  const int mtile = wg >> 5;
  const int m0 = mtile * FTILE;
  const int n0 = ntile * FTILE;

  f32x4 acc[4][4] = {};

  for (int k0 = 0; k0 < KDIM; k0 += FBK) {
    __syncthreads();
#pragma unroll
    for (int r = 0; r < 8; ++r) {
      const int f   = r * 256 + t;
      const int row = f >> 4;
      const int c4  = (f & 15) * 4;
      f32x4 v = *(const f32x4*)(X + (size_t)(m0 + row) * KDIM + (k0 + c4));
      s16x4 h;
#pragma unroll
      for (int j = 0; j < 4; ++j) h[j] = f32_to_bf16_rn(v[j]);
      *(s16x4*)&As[row * FBK + c4] = h;

      i32x4 wv = *(const i32x4*)(W + (size_t)(n0 + row) * KDIM + (k0 + c4));
      s16x4 hw;
#pragma unroll
      for (int j = 0; j < 4; ++j) hw[j] = f32_to_bf16_rn((float)wv[j]);
      *(s16x4*)&Bs[row * FBK + c4] = hw;
    }
    __syncthreads();

#pragma unroll
    for (int kk = 0; kk < FBK; kk += 32) {
      const int kb = kk + laneHalf * 8;
      using s16x8f = __attribute__((ext_vector_type(8))) short;
      s16x8f af[4], bf[4];
#pragma unroll
      for (int i = 0; i < 4; ++i) {
        af[i] = *(const s16x8f*)&As[(wm * 64 + i * 16 + lane15) * FBK + kb];
        bf[i] = *(const s16x8f*)&Bs[(wn * 64 + i * 16 + lane15) * FBK + kb];
      }
#pragma unroll
      for (int i = 0; i < 4; ++i)
#pragma unroll
        for (int j = 0; j < 4; ++j)
          acc[i][j] = __builtin_amdgcn_mfma_f32_16x16x32_bf16(af[i], bf[j], acc[i][j], 0, 0, 0);
    }
  }

  const float s = scale_p[0];
#pragma unroll
  for (int j = 0; j < 4; ++j) {
    const int col = n0 + wn * 64 + j * 16 + lane15;
    const float bv = bias[col];
#pragma unroll
    for (int i = 0; i < 4; ++i) {
      const int row = m0 + wm * 64 + i * 16 + laneHalf * 4;
#pragma unroll
      for (int q = 0; q < 4; ++q)
        out[(size_t)(row + q) * NDIM + col] = acc[i][j][q] * s + bv;
    }
  }
}

extern "C" void kernel_launch(void* const* d_in, const int* in_sizes, int n_in,
                              void* d_out, int out_size, void* d_ws, size_t ws_size,
                              hipStream_t stream) {
  const float* x     = (const float*)d_in[0];
  const int*   w     = (const int*)d_in[1];    // integer inputs materialize as int32
  const float* scale = (const float*)d_in[2];
  const float* bias  = (const float*)d_in[3];
  float* out = (float*)d_out;

  const size_t a_bytes = (size_t)MDIM * KDIM;            // 33,554,432 (i8)
  const size_t b_bytes = (size_t)NDIM * KDIM;            // 16,777,216 (i8)
  const size_t need    = a_bytes + b_bytes + MDIM * 4;   // + sx floats

  if (ws_size >= need) {
    signed char* Ai8 = (signed char*)d_ws;
    signed char* Bi8 = Ai8 + a_bytes;
    float*       sxp = (float*)(Bi8 + b_bytes);
    quant_x_kernel<<<MDIM, 256, 0, stream>>>(x, Ai8, sxp);
    quant_w_kernel<<<4096, 256, 0, stream>>>(w, Bi8, (int)(b_bytes / 16));
    const int nwg = (MDIM / 256) * (NDIM / 256);  // 32*16 = 512
    gemm_i8_8ph<<<nwg, 512, 0, stream>>>(Ai8, Bi8, sxp, scale, bias, out);
  } else {
    const int nwg = (MDIM / FTILE) * (NDIM / FTILE);  // 2048
    gemm_raw<<<nwg, 256, 0, stream>>>(x, w, scale, bias, out);
  }
}